// Round 4
// baseline (141.375 us; speedup 1.0000x reference)
//
#include <hip/hip_runtime.h>
#include <cstddef>

#define B_    4
#define CIN_  256
#define COUT_ 256
#define H_    64
#define W_    64
#define KK_   9
#define G_    4
#define NSL   36          // 4 groups * 9 taps, K=64 each
#define PW    80          // padded row width  (pad 8 each side)
#define PH    80          // padded rows       (pad 8 each side)
#define PADO  8           // pad offset

typedef short bf16x8 __attribute__((ext_vector_type(8)));
typedef float f32x4  __attribute__((ext_vector_type(4)));
typedef __attribute__((address_space(1))) const unsigned int* gptr_t;
typedef __attribute__((address_space(3))) unsigned int*       lptr_t;

__device__ __forceinline__ unsigned short f2bf(float v) {
    unsigned int u = __float_as_uint(v);
    u += 0x7fffu + ((u >> 16) & 1u);
    return (unsigned short)(u >> 16);
}
__device__ __forceinline__ float f_lo(unsigned int u) { return __uint_as_float(u << 16); }
__device__ __forceinline__ float f_hi(unsigned int u) { return __uint_as_float(u & 0xffff0000u); }

// Merged prep:
//   blocks [0,512):    xTp interior: [b][y'][x'][c] bf16, y'=h+8, x' in [0,80)
//                      (x-borders written as zeros by the same block)
//   blocks [512,576):  xTp border rows (y' in [0,8) u [72,80)) zero-fill
//   blocks [576,2880): wb weight repack (36 tiles, pos-swizzled)
__global__ __launch_bounds__(256) void prep_kernel(const float* __restrict__ x,
                                                   unsigned short* __restrict__ xTp,
                                                   const float* __restrict__ w,
                                                   unsigned short* __restrict__ wb) {
    const int tid = threadIdx.x;
    if (blockIdx.x < 512) {
        __shared__ unsigned short s[128][66];
        const int bh    = blockIdx.x >> 1;
        const int chalf = blockIdx.x & 1;
        const int b     = bh >> 6, h = bh & 63;
        const size_t src_base = ((size_t)b * CIN_ + chalf * 128) * (H_ * W_) + h * W_;
        #pragma unroll 4
        for (int k = 0; k < 32; ++k) {
            int i = k * 256 + tid;
            int c = i >> 6, ww = i & 63;
            s[c][ww] = f2bf(x[src_base + (size_t)c * (H_ * W_) + ww]);
        }
        __syncthreads();
        const size_t dst_row = ((size_t)b * PH + (h + PADO)) * PW;
        #pragma unroll 4
        for (int k = 0; k < 20; ++k) {              // 80 w' x 64 ch-pairs
            int j  = k * 256 + tid;
            int c2 = (j & 63) * 2, wp = j >> 6;     // wp in [0,80)
            unsigned int v = 0;
            if (wp >= PADO && wp < PADO + W_) {
                int ww = wp - PADO;
                v = (unsigned int)s[c2][ww] | ((unsigned int)s[c2 + 1][ww] << 16);
            }
            *(unsigned int*)(xTp + (dst_row + wp) * 256 + chalf * 128 + c2) = v;
        }
    } else if (blockIdx.x < 576) {
        const int bidx = blockIdx.x - 512;          // [0,64)
        const int b = bidx >> 4, rr = bidx & 15;
        const int yp = (rr < PADO) ? rr : (PH - 16 + rr);   // 0..7 or 72..79
        unsigned short* dst = xTp + ((size_t)b * PH + yp) * PW * 256;
        #pragma unroll
        for (int k = 0; k < 10; ++k) {              // 80*256 shorts = 2560 x 16B
            *(uint4*)(dst + (size_t)(k * 256 + tid) * 8) = make_uint4(0, 0, 0, 0);
        }
    } else {
        int idx = (blockIdx.x - 576) * 256 + tid;   // 36*16384 exactly
        int e   = idx & 7;
        int pos = (idx >> 3) & 7;
        int o   = (idx >> 6) & 255;
        int t   = idx >> 14;                        // g*9 + kk
        int g   = t / 9, kk = t - g * 9;
        int j   = pos ^ (o & 7);
        int c   = g * 64 + j * 8 + e;
        wb[idx] = f2bf(w[(o * CIN_ + c) * KK_ + kk]);
    }
}

// Main kernel: 256 blocks x 1024 threads (16 waves/CU = 4/SIMD).
// Block = (b,h): 256 outs x 64 px, full K (36 steps). Zero-padded xTp kills
// all bounds masks/clamps. 3-buffer W pipeline, counted vmcnt (DMA never
// drained to 0 in the loop). Sampling: 16 thr/px x 4ch (dwordx2 gathers).
__global__ __launch_bounds__(1024, 4) void dcn_kernel(
    const unsigned short* __restrict__ xTp, const float* __restrict__ y,
    const float* __restrict__ w_off, const unsigned short* __restrict__ wb,
    float* __restrict__ out)
{
    __shared__ unsigned short s_W[3][COUT_ * 64];   // 3 x 32 KB
    __shared__ unsigned short s_S[2][64 * 64];      // 2 x  8 KB

    const int tid = threadIdx.x;
    const int bid = blockIdx.x;                 // 256 blocks = 1/CU
    const int xcd = bid & 7;
    const int b   = xcd >> 1;
    const int h   = (xcd & 1) * 32 + (bid >> 3);

    // sampling mapping: 16 threads per pixel, 4 channels (8B) each
    const int sp = tid >> 4;          // pixel 0..63
    const int c4 = tid & 15;          // 4-ch chunk 0..15

    const float yv0 = y[((b * 2 + 0) * H_ + h) * W_ + sp];
    const float yv1 = y[((b * 2 + 1) * H_ + h) * W_ + sp];
    const float spf = (float)(sp - 1 + PADO);       // x base (pre-padded)
    const float hpf = (float)(h - 1 + PADO);        // y base (pre-padded)

    // mfma mapping: 16 waves, wave = 32 outs (oh) x 32 px (pg)
    const int lane = tid & 63, wave = tid >> 6;
    const int pg  = wave & 1, oh = wave >> 1;       // oh 0..7
    const int l15 = lane & 15, kq = lane >> 4, sw = l15 & 7;

    f32x4 acc[4];   // [nt][mt] : 2 px-subtiles x 2 out-subtiles
    #pragma unroll
    for (int i = 0; i < 4; ++i) acc[i] = (f32x4){0.f, 0.f, 0.f, 0.f};

    // wave-uniform batch base + per-thread channel offset (32-bit voffsets)
    const unsigned short* xb = xTp + (size_t)b * (PH * PW * 256) + c4 * 4;

    // in-flight sample state for the next step
    float w00, w01, w10, w11;
    uint2 A, Bv, C, D;

#define ISSUE_SAMPLE(t) do {                                                   \
    const int g_ = (t) / 9, kk_ = (t) % 9;                                     \
    const float4 co = *(const float4*)(w_off + (t) * 4);                       \
    const float dy = fmaf(yv0, co.x, yv1 * co.y);                              \
    const float dx = fmaf(yv0, co.z, yv1 * co.w);                              \
    const float yc = hpf + (float)(kk_ / 3) + dy;                              \
    const float xc = spf + (float)(kk_ % 3) + dx;                              \
    const float yf = floorf(yc), xf = floorf(xc);                              \
    const float wy = yc - yf,    wx = xc - xf;                                 \
    const int   yi = (int)yf,    xi = (int)xf;      /* padded coords, >=0 */   \
    const float omy = 1.f - wy,  omx = 1.f - wx;                               \
    w00 = omy * omx;  w01 = omy * wx;                                          \
    w10 = wy * omx;   w11 = wy * wx;                                           \
    const int idx0 = (yi * PW + xi) * 256 + g_ * 64;   /* shorts */            \
    A  = *(const uint2*)(xb + idx0);                                           \
    Bv = *(const uint2*)(xb + idx0 + 256);             /* x+1: +512B imm */    \
    C  = *(const uint2*)(xb + idx0 + PW * 256);        /* y+1 */               \
    D  = *(const uint2*)(xb + idx0 + PW * 256 + 256);                          \
} while (0)

#define STAGE_W(t, buf) do {                                                   \
    const unsigned short* src = wb + (size_t)(t) * 16384;                      \
    _Pragma("unroll")                                                          \
    for (int j = 0; j < 2; ++j) {                                              \
        const int off = (j * 1024 + tid) * 8;                                  \
        __builtin_amdgcn_global_load_lds((gptr_t)(src + off),                  \
                                         (lptr_t)(s_W[buf] + off), 16, 0, 2); \
    }                                                                          \
} while (0)

#define WRITE_SAMPLE(buf) do {                                                 \
    float r0 = w00 * f_lo(A.x);                                                \
    r0 = fmaf(w01, f_lo(Bv.x), r0);                                            \
    r0 = fmaf(w10, f_lo(C.x),  r0);                                            \
    r0 = fmaf(w11, f_lo(D.x),  r0);                                            \
    float r1 = w00 * f_hi(A.x);                                                \
    r1 = fmaf(w01, f_hi(Bv.x), r1);                                            \
    r1 = fmaf(w10, f_hi(C.x),  r1);                                            \
    r1 = fmaf(w11, f_hi(D.x),  r1);                                            \
    float r2 = w00 * f_lo(A.y);                                                \
    r2 = fmaf(w01, f_lo(Bv.y), r2);                                            \
    r2 = fmaf(w10, f_lo(C.y),  r2);                                            \
    r2 = fmaf(w11, f_lo(D.y),  r2);                                            \
    float r3 = w00 * f_hi(A.y);                                                \
    r3 = fmaf(w01, f_hi(Bv.y), r3);                                            \
    r3 = fmaf(w10, f_hi(C.y),  r3);                                            \
    r3 = fmaf(w11, f_hi(D.y),  r3);                                            \
    unsigned int res0 = __builtin_amdgcn_perm(__float_as_uint(r1),             \
                                __float_as_uint(r0), 0x07060302u);             \
    unsigned int res1 = __builtin_amdgcn_perm(__float_as_uint(r3),             \
                                __float_as_uint(r2), 0x07060302u);             \
    *(uint2*)(s_S[buf] + sp * 64 + (((c4 >> 1) ^ (sp & 7)) * 8) +              \
              (c4 & 1) * 4) = make_uint2(res0, res1);                          \
} while (0)

#define MFMA_STEP(wb_, sb_) do {                                               \
    bf16x8 bf[2][2], af[2][2];                                                 \
    _Pragma("unroll")                                                          \
    for (int kh = 0; kh < 2; ++kh) {                                           \
        const int pos = ((kh * 4 + kq) ^ sw) * 8;                              \
        _Pragma("unroll")                                                      \
        for (int nt = 0; nt < 2; ++nt)                                         \
            bf[kh][nt] = *(const bf16x8*)(s_S[sb_] +                           \
                              (pg * 32 + nt * 16 + l15) * 64 + pos);           \
        _Pragma("unroll")                                                      \
        for (int mt = 0; mt < 2; ++mt)                                         \
            af[kh][mt] = *(const bf16x8*)(s_W[wb_] +                           \
                              (oh * 32 + mt * 16 + l15) * 64 + pos);           \
    }                                                                          \
    __builtin_amdgcn_s_setprio(1);                                             \
    _Pragma("unroll")                                                          \
    for (int kh = 0; kh < 2; ++kh)                                             \
        _Pragma("unroll")                                                      \
        for (int nt = 0; nt < 2; ++nt)                                         \
            _Pragma("unroll")                                                  \
            for (int mt = 0; mt < 2; ++mt)                                     \
                acc[nt * 2 + mt] = __builtin_amdgcn_mfma_f32_16x16x32_bf16(    \
                    af[kh][mt], bf[kh][nt], acc[nt * 2 + mt], 0, 0, 0);        \
    __builtin_amdgcn_s_setprio(0);                                             \
} while (0)

// One step. WCUR = s%3 (MFMA source), WPRE = (s+2)%3 (DMA dest),
// SCUR = s%2 (MFMA B-source), SNXT = (s+1)%2 (sample dest).
// Invariant entering step s: DMA(s+1) is the only outstanding vmem (2 instrs).
// WRITE_SAMPLE's compiler-wait on the gathers (vmcnt(2): 2 DMA issued after
// them) retires DMA(s+1); DMA(s+2) crosses the barrier in flight.
#define STEP(s_, WCUR, WPRE, SCUR, SNXT, DO_ISS, DO_STG, DO_BAR) do {          \
    if (DO_ISS) ISSUE_SAMPLE((s_) + 1);                                        \
    __builtin_amdgcn_sched_barrier(0);                                         \
    if (DO_STG) STAGE_W((s_) + 2, WPRE);                                       \
    __builtin_amdgcn_sched_barrier(0);                                         \
    MFMA_STEP(WCUR, SCUR);                                                     \
    __builtin_amdgcn_sched_barrier(0);                                         \
    if (DO_ISS) WRITE_SAMPLE(SNXT);                                            \
    __builtin_amdgcn_sched_barrier(0);                                         \
    if (DO_BAR) {                                                              \
        asm volatile("s_waitcnt lgkmcnt(0)" ::: "memory");                     \
        __builtin_amdgcn_sched_barrier(0);                                     \
        __builtin_amdgcn_s_barrier();                                          \
        __builtin_amdgcn_sched_barrier(0);                                     \
    }                                                                          \
} while (0)

    // ---- prologue: stage steps 0,1; leave DMA(1) in flight at the barrier ----
    ISSUE_SAMPLE(0);
    __builtin_amdgcn_sched_barrier(0);
    STAGE_W(0, 0);
    __builtin_amdgcn_sched_barrier(0);
    WRITE_SAMPLE(0);                 // waits gathers(0) [vmcnt(2)]; leaves DMA(0)
    __builtin_amdgcn_sched_barrier(0);
    STAGE_W(1, 1);
    __builtin_amdgcn_sched_barrier(0);
    asm volatile("s_waitcnt vmcnt(2) lgkmcnt(0)" ::: "memory");  // DMA(0) done
    __builtin_amdgcn_sched_barrier(0);
    __builtin_amdgcn_s_barrier();
    __builtin_amdgcn_sched_barrier(0);

    // ---- main loop: 5 x 6 steps (buffer indices static), then 6-step tail ----
    for (int sb = 0; sb < 30; sb += 6) {
        STEP(sb + 0, 0, 2, 0, 1, 1, 1, 1);
        STEP(sb + 1, 1, 0, 1, 0, 1, 1, 1);
        STEP(sb + 2, 2, 1, 0, 1, 1, 1, 1);
        STEP(sb + 3, 0, 2, 1, 0, 1, 1, 1);
        STEP(sb + 4, 1, 0, 0, 1, 1, 1, 1);
        STEP(sb + 5, 2, 1, 1, 0, 1, 1, 1);
    }
    STEP(30, 0, 2, 0, 1, 1, 1, 1);
    STEP(31, 1, 0, 1, 0, 1, 1, 1);
    STEP(32, 2, 1, 0, 1, 1, 1, 1);
    STEP(33, 0, 2, 1, 0, 1, 1, 1);
    STEP(34, 1, 0, 0, 1, 1, 0, 1);   // no STAGE(36): WRITE(35) drains DMA(35)
    STEP(35, 2, 1, 1, 0, 0, 0, 0);   // last MFMA; no barrier before epilogue

    // ---- epilogue: fused relu, direct final store. C/D: col->px, row->o ----
    #pragma unroll
    for (int nt = 0; nt < 2; ++nt) {
        const int px = pg * 32 + nt * 16 + l15;
        #pragma unroll
        for (int mt = 0; mt < 2; ++mt) {
            const int obase = oh * 32 + mt * 16 + kq * 4;
            #pragma unroll
            for (int rr = 0; rr < 4; ++rr) {
                out[(((size_t)b * COUT_ + obase + rr) * H_ + h) * W_ + px] =
                    fmaxf(acc[nt * 2 + mt][rr], 0.f);
            }
        }
    }
#undef ISSUE_SAMPLE
#undef STAGE_W
#undef WRITE_SAMPLE
#undef MFMA_STEP
#undef STEP
}

extern "C" void kernel_launch(void* const* d_in, const int* in_sizes, int n_in,
                              void* d_out, int out_size, void* d_ws, size_t ws_size,
                              hipStream_t stream) {
    const float* x     = (const float*)d_in[0];
    const float* y     = (const float*)d_in[1];
    const float* w_off = (const float*)d_in[2];
    const float* w_def = (const float*)d_in[3];
    float* out = (float*)d_out;

    unsigned short* xTp = (unsigned short*)d_ws;            // 4*80*80*256*2B = 13.1 MB
    unsigned short* wb  = (unsigned short*)d_ws + (size_t)B_ * PH * PW * 256;  // 1.18 MB

    prep_kernel<<<2880, 256, 0, stream>>>(x, xTp, w_def, wb);
    dcn_kernel<<<256, 1024, 0, stream>>>(xTp, y, w_off, wb, out);
}

// Round 5
// 132.644 us; speedup vs baseline: 1.0658x; 1.0658x over previous
//
#include <hip/hip_runtime.h>
#include <cstddef>

#define B_    4
#define CIN_  256
#define COUT_ 256
#define H_    64
#define W_    64
#define KK_   9
#define G_    4
#define NSL   36          // 4 groups * 9 taps, K=64 each
#define PW    80          // padded row width  (pad 8 each side)
#define PH    80          // padded rows       (pad 8 each side)
#define PADO  8           // pad offset

typedef short bf16x8 __attribute__((ext_vector_type(8)));
typedef float f32x4  __attribute__((ext_vector_type(4)));
typedef __attribute__((address_space(1))) const unsigned int* gptr_t;
typedef __attribute__((address_space(3))) unsigned int*       lptr_t;

__device__ __forceinline__ unsigned short f2bf(float v) {
    unsigned int u = __float_as_uint(v);
    u += 0x7fffu + ((u >> 16) & 1u);
    return (unsigned short)(u >> 16);
}
__device__ __forceinline__ float f_lo(unsigned int u) { return __uint_as_float(u << 16); }
__device__ __forceinline__ float f_hi(unsigned int u) { return __uint_as_float(u & 0xffff0000u); }

// Merged prep:
//   blocks [0,512):    xTp interior rows (x-borders zeroed inline)
//   blocks [512,576):  xTp border rows zero-fill
//   blocks [576,2880): wb weight repack (36 tiles, pos-swizzled)
__global__ __launch_bounds__(256) void prep_kernel(const float* __restrict__ x,
                                                   unsigned short* __restrict__ xTp,
                                                   const float* __restrict__ w,
                                                   unsigned short* __restrict__ wb) {
    const int tid = threadIdx.x;
    if (blockIdx.x < 512) {
        __shared__ unsigned short s[128][66];
        const int bh    = blockIdx.x >> 1;
        const int chalf = blockIdx.x & 1;
        const int b     = bh >> 6, h = bh & 63;
        const size_t src_base = ((size_t)b * CIN_ + chalf * 128) * (H_ * W_) + h * W_;
        #pragma unroll 4
        for (int k = 0; k < 32; ++k) {
            int i = k * 256 + tid;
            int c = i >> 6, ww = i & 63;
            s[c][ww] = f2bf(x[src_base + (size_t)c * (H_ * W_) + ww]);
        }
        __syncthreads();
        const size_t dst_row = ((size_t)b * PH + (h + PADO)) * PW;
        #pragma unroll 4
        for (int k = 0; k < 20; ++k) {              // 80 w' x 64 ch-pairs
            int j  = k * 256 + tid;
            int c2 = (j & 63) * 2, wp = j >> 6;     // wp in [0,80)
            unsigned int v = 0;
            if (wp >= PADO && wp < PADO + W_) {
                int ww = wp - PADO;
                v = (unsigned int)s[c2][ww] | ((unsigned int)s[c2 + 1][ww] << 16);
            }
            *(unsigned int*)(xTp + (dst_row + wp) * 256 + chalf * 128 + c2) = v;
        }
    } else if (blockIdx.x < 576) {
        const int bidx = blockIdx.x - 512;          // [0,64)
        const int b = bidx >> 4, rr = bidx & 15;
        const int yp = (rr < PADO) ? rr : (PH - 16 + rr);   // 0..7 or 72..79
        unsigned short* dst = xTp + ((size_t)b * PH + yp) * PW * 256;
        #pragma unroll
        for (int k = 0; k < 10; ++k) {              // 80*256 shorts = 2560 x 16B
            *(uint4*)(dst + (size_t)(k * 256 + tid) * 8) = make_uint4(0, 0, 0, 0);
        }
    } else {
        int idx = (blockIdx.x - 576) * 256 + tid;   // 36*16384 exactly
        int e   = idx & 7;
        int pos = (idx >> 3) & 7;
        int o   = (idx >> 6) & 255;
        int t   = idx >> 14;                        // g*9 + kk
        int g   = t / 9, kk = t - g * 9;
        int j   = pos ^ (o & 7);
        int c   = g * 64 + j * 8 + e;
        wb[idx] = f2bf(w[(o * CIN_ + c) * KK_ + kk]);
    }
}

// Main kernel: 256 blocks x 512 threads (8 waves), 1 block/CU, LDS 112 KB.
// Block = (b,h): 256 outs x 64 px, 36 K-steps. TWO-STEP-AHEAD gather pipeline:
// step s issues gathers(s+2) + DMA W(s+2), MFMAs step s, writes S(s+1) from
// registers gathered one full step earlier. Counted vmcnt(8) at the barrier --
// G(s+2)+DMA(s+2) stay in flight; nothing drains to 0 until the tail.
__global__ __launch_bounds__(512, 2) void dcn_kernel(
    const unsigned short* __restrict__ xTp, const float* __restrict__ y,
    const float* __restrict__ w_off, const unsigned short* __restrict__ wb,
    float* __restrict__ out)
{
    __shared__ unsigned short s_W[3][COUT_ * 64];   // 3 x 32 KB
    __shared__ unsigned short s_S[2][64 * 64];      // 2 x  8 KB

    const int tid = threadIdx.x;
    const int bid = blockIdx.x;                 // 256 blocks = 1/CU
    const int xcd = bid & 7;
    const int b   = xcd >> 1;
    const int h   = (xcd & 1) * 32 + (bid >> 3);

    // sampling mapping: 8 threads per pixel, 8 channels (16B) each
    const int sp = tid >> 3;          // pixel 0..63
    const int c8 = tid & 7;           // 8-ch chunk 0..7

    const float yv0 = y[((b * 2 + 0) * H_ + h) * W_ + sp];
    const float yv1 = y[((b * 2 + 1) * H_ + h) * W_ + sp];
    const float spf = (float)(sp - 1 + PADO);       // x base (pre-padded)
    const float hpf = (float)(h - 1 + PADO);        // y base (pre-padded)

    // mfma mapping: 8 waves, wave = 64 outs (oh) x 32 px (pg)
    const int lane = tid & 63, wave = tid >> 6;
    const int pg  = wave & 1, oh = wave >> 1;       // oh 0..3
    const int l15 = lane & 15, kq = lane >> 4, sw = l15 & 7;

    f32x4 acc[8];   // [nt][mt] : 2 px-subtiles x 4 out-subtiles
    #pragma unroll
    for (int i = 0; i < 8; ++i) acc[i] = (f32x4){0.f, 0.f, 0.f, 0.f};

    const unsigned short* xb = xTp + (size_t)b * (PH * PW * 256) + c8 * 8;

    // two in-flight sample states (static indices only -- rule #20)
    float w00[2], w01[2], w10[2], w11[2];
    uint4 A[2], Bv[2], C[2], D[2];

#define ISSUE_SAMPLE(t, P) do {                                                \
    const int g_ = (t) / 9, kk_ = (t) % 9;                                     \
    const float4 co = *(const float4*)(w_off + (t) * 4);                       \
    const float dy = fmaf(yv0, co.x, yv1 * co.y);                              \
    const float dx = fmaf(yv0, co.z, yv1 * co.w);                              \
    const float yc = hpf + (float)(kk_ / 3) + dy;                              \
    const float xc = spf + (float)(kk_ % 3) + dx;                              \
    const float yf = floorf(yc), xf = floorf(xc);                              \
    const float wy = yc - yf,    wx = xc - xf;                                 \
    const int   yi = (int)yf,    xi = (int)xf;      /* padded coords, >=0 */   \
    const float omy = 1.f - wy,  omx = 1.f - wx;                               \
    w00[P] = omy * omx;  w01[P] = omy * wx;                                    \
    w10[P] = wy * omx;   w11[P] = wy * wx;                                     \
    const int idx0 = (yi * PW + xi) * 256 + g_ * 64;   /* shorts */            \
    A[P]  = *(const uint4*)(xb + idx0);                                        \
    Bv[P] = *(const uint4*)(xb + idx0 + 256);                                  \
    C[P]  = *(const uint4*)(xb + idx0 + PW * 256);                             \
    D[P]  = *(const uint4*)(xb + idx0 + PW * 256 + 256);                       \
} while (0)

#define STAGE_W(t, buf) do {                                                   \
    const unsigned short* src = wb + (size_t)(t) * 16384;                      \
    _Pragma("unroll")                                                          \
    for (int j = 0; j < 4; ++j) {                                              \
        const int off = (j * 512 + tid) * 8;                                   \
        __builtin_amdgcn_global_load_lds((gptr_t)(src + off),                  \
                                         (lptr_t)(s_W[buf] + off), 16, 0, 2); \
    }                                                                          \
} while (0)

#define WRITE_SAMPLE(P, buf) do {                                              \
    const unsigned int av[4] = {A[P].x, A[P].y, A[P].z, A[P].w};               \
    const unsigned int bv[4] = {Bv[P].x, Bv[P].y, Bv[P].z, Bv[P].w};           \
    const unsigned int cv[4] = {C[P].x, C[P].y, C[P].z, C[P].w};               \
    const unsigned int dv[4] = {D[P].x, D[P].y, D[P].z, D[P].w};               \
    unsigned int res[4];                                                       \
    _Pragma("unroll")                                                          \
    for (int q = 0; q < 4; ++q) {                                              \
        float rl = w00[P] * f_lo(av[q]);                                       \
        rl = fmaf(w01[P], f_lo(bv[q]), rl);                                    \
        rl = fmaf(w10[P], f_lo(cv[q]), rl);                                    \
        rl = fmaf(w11[P], f_lo(dv[q]), rl);                                    \
        float rh = w00[P] * f_hi(av[q]);                                       \
        rh = fmaf(w01[P], f_hi(bv[q]), rh);                                    \
        rh = fmaf(w10[P], f_hi(cv[q]), rh);                                    \
        rh = fmaf(w11[P], f_hi(dv[q]), rh);                                    \
        res[q] = __builtin_amdgcn_perm(__float_as_uint(rh),                    \
                                       __float_as_uint(rl), 0x07060302u);      \
    }                                                                          \
    *(uint4*)(s_S[buf] + sp * 64 + ((c8 ^ (sp & 7)) * 8)) =                    \
        make_uint4(res[0], res[1], res[2], res[3]);                            \
} while (0)

#define MFMA_STEP(wb_, sb_) do {                                               \
    bf16x8 bf[2][2], af[2][4];                                                 \
    _Pragma("unroll")                                                          \
    for (int kh = 0; kh < 2; ++kh) {                                           \
        const int pos = ((kh * 4 + kq) ^ sw) * 8;                              \
        _Pragma("unroll")                                                      \
        for (int nt = 0; nt < 2; ++nt)                                         \
            bf[kh][nt] = *(const bf16x8*)(s_S[sb_] +                           \
                              (pg * 32 + nt * 16 + l15) * 64 + pos);           \
        _Pragma("unroll")                                                      \
        for (int mt = 0; mt < 4; ++mt)                                         \
            af[kh][mt] = *(const bf16x8*)(s_W[wb_] +                           \
                              (oh * 64 + mt * 16 + l15) * 64 + pos);           \
    }                                                                          \
    __builtin_amdgcn_s_setprio(1);                                             \
    _Pragma("unroll")                                                          \
    for (int kh = 0; kh < 2; ++kh)                                             \
        _Pragma("unroll")                                                      \
        for (int nt = 0; nt < 2; ++nt)                                         \
            _Pragma("unroll")                                                  \
            for (int mt = 0; mt < 4; ++mt)                                     \
                acc[nt * 4 + mt] = __builtin_amdgcn_mfma_f32_16x16x32_bf16(    \
                    af[kh][mt], bf[kh][nt], acc[nt * 4 + mt], 0, 0, 0);        \
    __builtin_amdgcn_s_setprio(0);                                             \
} while (0)

// Step s. Per-wave outstanding vmem entering step s: G(s+1)[4] + DMA(s+1)[4].
// Issue G(s+2)[4], DMA(s+2)[4] -> 16 outstanding. WRITE(s+1)'s compiler-wait
// on G(s+1) regs = vmcnt(12) (retires exactly G(s+1), oldest-first). Explicit
// end wait vmcnt(8) retires DMA(s+1); G(s+2)+DMA(s+2) cross the barrier.
#define STEP(s_, WCUR, WPRE, SCUR, SNXT, PiS, PwR, DO_PF, END8) do {           \
    if (DO_PF) ISSUE_SAMPLE((s_) + 2, PiS);                                    \
    __builtin_amdgcn_sched_barrier(0);                                         \
    if (DO_PF) STAGE_W((s_) + 2, WPRE);                                        \
    __builtin_amdgcn_sched_barrier(0);                                         \
    MFMA_STEP(WCUR, SCUR);                                                     \
    __builtin_amdgcn_sched_barrier(0);                                         \
    WRITE_SAMPLE(PwR, SNXT);                                                   \
    __builtin_amdgcn_sched_barrier(0);                                         \
    if (END8) asm volatile("s_waitcnt vmcnt(8) lgkmcnt(0)" ::: "memory");      \
    else      asm volatile("s_waitcnt vmcnt(0) lgkmcnt(0)" ::: "memory");      \
    __builtin_amdgcn_sched_barrier(0);                                         \
    __builtin_amdgcn_s_barrier();                                              \
    __builtin_amdgcn_sched_barrier(0);                                         \
} while (0)

    // ---- prologue: G(0),W(0),G(1),W(1); write S(0); leave G(1)+DMA(1) ----
    ISSUE_SAMPLE(0, 0);
    __builtin_amdgcn_sched_barrier(0);
    STAGE_W(0, 0);
    __builtin_amdgcn_sched_barrier(0);
    ISSUE_SAMPLE(1, 1);
    __builtin_amdgcn_sched_barrier(0);
    STAGE_W(1, 1);
    __builtin_amdgcn_sched_barrier(0);
    WRITE_SAMPLE(0, 0);              // auto vmcnt(12): retires G(0)
    __builtin_amdgcn_sched_barrier(0);
    asm volatile("s_waitcnt vmcnt(8) lgkmcnt(0)" ::: "memory");  // DMA(0) done
    __builtin_amdgcn_sched_barrier(0);
    __builtin_amdgcn_s_barrier();
    __builtin_amdgcn_sched_barrier(0);

    // ---- main loop: 5 x 6 steps (all indices static), then 6-step tail ----
    // STEP(s, s%3, (s+2)%3, s%2, (s+1)%2, s&1, (s+1)&1, prefetch, counted)
    for (int sb = 0; sb < 30; sb += 6) {
        STEP(sb + 0, 0, 2, 0, 1, 0, 1, 1, 1);
        STEP(sb + 1, 1, 0, 1, 0, 1, 0, 1, 1);
        STEP(sb + 2, 2, 1, 0, 1, 0, 1, 1, 1);
        STEP(sb + 3, 0, 2, 1, 0, 1, 0, 1, 1);
        STEP(sb + 4, 1, 0, 0, 1, 0, 1, 1, 1);
        STEP(sb + 5, 2, 1, 1, 0, 1, 0, 1, 1);
    }
    STEP(30, 0, 2, 0, 1, 0, 1, 1, 1);
    STEP(31, 1, 0, 1, 0, 1, 0, 1, 1);
    STEP(32, 2, 1, 0, 1, 0, 1, 1, 1);
    STEP(33, 0, 2, 1, 0, 1, 0, 1, 1);
    STEP(34, 1, 0, 0, 1, 0, 1, 0, 0);   // no prefetch; drain all (W(35) ready)
    MFMA_STEP(2, 1);                    // step 35; no barrier before epilogue

    // ---- epilogue: fused relu, direct final store. C/D: col->px, row->o ----
    #pragma unroll
    for (int nt = 0; nt < 2; ++nt) {
        const int px = pg * 32 + nt * 16 + l15;
        #pragma unroll
        for (int mt = 0; mt < 4; ++mt) {
            const int obase = oh * 64 + mt * 16 + kq * 4;
            #pragma unroll
            for (int rr = 0; rr < 4; ++rr) {
                out[(((size_t)b * COUT_ + obase + rr) * H_ + h) * W_ + px] =
                    fmaxf(acc[nt * 4 + mt][rr], 0.f);
            }
        }
    }
#undef ISSUE_SAMPLE
#undef STAGE_W
#undef WRITE_SAMPLE
#undef MFMA_STEP
#undef STEP
}

extern "C" void kernel_launch(void* const* d_in, const int* in_sizes, int n_in,
                              void* d_out, int out_size, void* d_ws, size_t ws_size,
                              hipStream_t stream) {
    const float* x     = (const float*)d_in[0];
    const float* y     = (const float*)d_in[1];
    const float* w_off = (const float*)d_in[2];
    const float* w_def = (const float*)d_in[3];
    float* out = (float*)d_out;

    unsigned short* xTp = (unsigned short*)d_ws;            // 4*80*80*256*2B = 13.1 MB
    unsigned short* wb  = (unsigned short*)d_ws + (size_t)B_ * PH * PW * 256;  // 1.18 MB

    prep_kernel<<<2880, 256, 0, stream>>>(x, xTp, w_def, wb);
    dcn_kernel<<<256, 512, 0, stream>>>(xTp, y, w_off, wb, out);
}